// Round 1
// baseline (264.207 us; speedup 1.0000x reference)
//
#include <hip/hip_runtime.h>

#define L_LEN 16384
#define M_LEN 8192
#define LOGM 13
#define KT_LEN 4096
#define BB 32
#define NTPL 50
#define SPEC_STRIDE 8224   // complex slots per signal (>= 8193)
#define NSIG 166           // 64 x-signals + 2 w-signals + 100 templates
#define PI_F 3.14159265358979323846f

__device__ __forceinline__ float2 cmul(float2 a, float2 b) {
    return make_float2(a.x*b.x - a.y*b.y, a.x*b.y + a.y*b.x);
}
__device__ __forceinline__ float2 cmulc(float2 a, float2 b) { // a * conj(b)
    return make_float2(a.x*b.x + a.y*b.y, a.y*b.x - a.x*b.y);
}
__device__ __forceinline__ int brev13(int i) {
    return (int)(__brev((unsigned)i) >> 19);
}

// ---------------------------------------------------------------------------
// Kernel 1: forward real FFTs (length L) via half-length complex DIF FFT.
// One block per signal. Output: natural-order spectrum X[f], f=0..M (8193).
// Signals: 0..63 = xi[b,c]; 64..65 = S_t_m12[c]; 66..165 = template[n,c] (KT,
// zero-padded to L).
// ---------------------------------------------------------------------------
__global__ __launch_bounds__(512)
void fwd_fft_kernel(const float* __restrict__ xi, const float* __restrict__ w,
                    const float* __restrict__ tmpl, float2* __restrict__ spec) {
    __shared__ float2 A[M_LEN];   // 64 KB
    const int sig = blockIdx.x;
    const int tid = threadIdx.x;

    const float* src;
    int nre;
    if (sig < 64)      { src = xi   + sig * L_LEN;        nre = L_LEN; }
    else if (sig < 66) { src = w    + (sig - 64) * L_LEN; nre = L_LEN; }
    else               { src = tmpl + (sig - 66) * KT_LEN; nre = KT_LEN; }
    const int nc = nre >> 1;      // complex count after even/odd packing
    const float2* s2 = (const float2*)src;
    for (int i = tid; i < nc; i += 512)       A[i] = s2[i];
    for (int i = nc + tid; i < M_LEN; i += 512) A[i] = make_float2(0.f, 0.f);
    __syncthreads();

    // DIF FFT (e^{-i}), natural in -> bit-reversed out, in place.
    for (int s = 0; s < LOGM; ++s) {
        const int lh = LOGM - 1 - s;
        const int half = 1 << lh;
        for (int it = tid; it < M_LEN/2; it += 512) {
            const int j = it & (half - 1);
            const int p = ((it >> lh) << (lh + 1)) + j;
            float2 u = A[p], v = A[p + half];
            float2 d = make_float2(u.x - v.x, u.y - v.y);
            A[p] = make_float2(u.x + v.x, u.y + v.y);
            float sn, cs;
            __sincosf(-PI_F * (float)j / (float)half, &sn, &cs);
            A[p + half] = make_float2(d.x*cs - d.y*sn, d.x*sn + d.y*cs);
        }
        __syncthreads();
    }

    // Untangle packed result to real-signal spectrum X[f], f = 0..M.
    float2* out = spec + (size_t)sig * SPEC_STRIDE;
    for (int f = tid; f <= M_LEN; f += 512) {
        const int fa = f & (M_LEN - 1);
        const int fb = (M_LEN - f) & (M_LEN - 1);
        float2 Za = A[brev13(fa)];
        float2 Zb = A[brev13(fb)];
        float2 E = make_float2(0.5f*(Za.x + Zb.x), 0.5f*(Za.y - Zb.y));
        float2 D = make_float2(Za.x - Zb.x, Za.y + Zb.y);
        float2 O = make_float2(0.5f*D.y, -0.5f*D.x);      // -i/2 * D
        float sn, cs;
        __sincosf(-PI_F * (float)f / (float)M_LEN, &sn, &cs);
        float2 TO = make_float2(cs*O.x - sn*O.y, cs*O.y + sn*O.x);
        out[f] = make_float2(E.x + TO.x, E.y + TO.y);
    }
}

// ---------------------------------------------------------------------------
// Kernel 2: per (b,n,c): S[f] = X·conj(W)·conj(H)·e^{-2pi i*(KT-2)*f/L},
// real inverse FFT via half-length complex inverse DIF (output order
// irrelevant — we only need max over t), then max / hh_sqrt.
// ---------------------------------------------------------------------------
__global__ __launch_bounds__(512)
void inv_fft_kernel(const float2* __restrict__ spec, const float* __restrict__ hh,
                    float* __restrict__ zarr) {
    __shared__ float2 A[M_LEN];   // 64 KB (also reused for final reduction)
    const int idx = blockIdx.x;
    const int c = idx & 1;
    const int n = (idx >> 1) % NTPL;
    const int b = idx / (2 * NTPL);
    const int tid = threadIdx.x;

    const float2* Xs = spec + (size_t)(b*2 + c)      * SPEC_STRIDE;
    const float2* Ws = spec + (size_t)(64 + c)       * SPEC_STRIDE;
    const float2* Hs = spec + (size_t)(66 + n*2 + c) * SPEC_STRIDE;

    // Pass 1: S[f] for f=0..M-1 into LDS; S[M] stays in a register of tid 0
    // (f=8192 is handled by tid 0 since 8192 % 512 == 0).
    float2 SMreg = make_float2(0.f, 0.f);
    for (int f = tid; f <= M_LEN; f += 512) {
        float2 X = Xs[f], Wc = Ws[f], Hc = Hs[f];
        float2 t = cmulc(X, Wc);
        t = cmulc(t, Hc);
        const int k = (4094 * f) & (L_LEN - 1);   // (KT-2)*f mod L, exact
        float sn, cs;
        __sincosf(-PI_F * (float)k / (float)M_LEN, &sn, &cs);
        float2 S = cmul(t, make_float2(cs, sn));
        if (f < M_LEN) A[f] = S; else SMreg = S;
    }
    __syncthreads();

    // Pass 2: pack Z'[f] (the half-length complex spectrum of the real dh).
    // Thread owning f in [0, M/2] writes Z'[f] and Z'[M-f]; pairs disjoint.
    for (int f = tid; f <= M_LEN/2; f += 512) {
        float2 Sa = A[f];
        float2 Sb = (f == 0) ? SMreg : A[M_LEN - f];
        float2 E = make_float2(0.5f*(Sa.x + Sb.x), 0.5f*(Sa.y - Sb.y));
        float2 D = make_float2(Sa.x - Sb.x, Sa.y + Sb.y);
        float sn, cs;
        __sincosf(PI_F * (float)f / (float)M_LEN, &sn, &cs);   // e^{+2pi i f/L}
        float2 O = make_float2(0.5f*(cs*D.x - sn*D.y), 0.5f*(cs*D.y + sn*D.x));
        float2 Zf = make_float2(E.x - O.y, E.y + O.x);
        A[f] = Zf;
        if (f > 0 && f < M_LEN/2)
            A[M_LEN - f] = make_float2(E.x + O.y, O.x - E.y);
    }
    __syncthreads();

    // Inverse DIF (e^{+i}), natural in -> bit-reversed out (order irrelevant).
    for (int s = 0; s < LOGM; ++s) {
        const int lh = LOGM - 1 - s;
        const int half = 1 << lh;
        for (int it = tid; it < M_LEN/2; it += 512) {
            const int j = it & (half - 1);
            const int p = ((it >> lh) << (lh + 1)) + j;
            float2 u = A[p], v = A[p + half];
            float2 d = make_float2(u.x - v.x, u.y - v.y);
            A[p] = make_float2(u.x + v.x, u.y + v.y);
            float sn, cs;
            __sincosf(PI_F * (float)j / (float)half, &sn, &cs);
            A[p + half] = make_float2(d.x*cs - d.y*sn, d.x*sn + d.y*cs);
        }
        __syncthreads();
    }

    // Max over all time samples (re and im parts of every entry).
    float m = -INFINITY;
    for (int i = tid; i < M_LEN; i += 512) {
        float2 v = A[i];
        m = fmaxf(m, fmaxf(v.x, v.y));
    }
    __syncthreads();   // all reads of A done before reusing it as scratch
    for (int off = 32; off > 0; off >>= 1)
        m = fmaxf(m, __shfl_xor(m, off));
    const int lane = tid & 63, wv = tid >> 6;
    float* redf = (float*)A;
    if (lane == 0) redf[wv] = m;
    __syncthreads();
    if (tid == 0) {
        float mm = redf[0];
        for (int i = 1; i < 8; ++i) mm = fmaxf(mm, redf[i]);
        // divide the unscaled IFFT by M, then by hh_sqrt (both positive).
        zarr[(b*2 + c)*NTPL + n] = mm / ((float)M_LEN * hh[n*2 + c]);
    }
}

// ---------------------------------------------------------------------------
// Kernel 3: tiny CNN/MLP head. One block per batch element.
// ---------------------------------------------------------------------------
__global__ __launch_bounds__(256)
void head_kernel(const float* __restrict__ zarr,
                 const float* __restrict__ W1, const float* __restrict__ b1,
                 const float* __restrict__ W2, const float* __restrict__ b2,
                 const float* __restrict__ W3, const float* __restrict__ b3,
                 const float* __restrict__ W4, const float* __restrict__ b4,
                 float* __restrict__ out) {
    __shared__ float zl[2][NTPL];
    __shared__ float s1[16][48];
    __shared__ float p1[16][16];
    __shared__ float s2[32][14];
    __shared__ float hflat[128];
    __shared__ float h1[32];
    const int b = blockIdx.x, tid = threadIdx.x;

    for (int i = tid; i < 2*NTPL; i += 256) zl[i/NTPL][i%NTPL] = zarr[b*2*NTPL + i];
    __syncthreads();
    // conv1 (2->16, K=3, pad 0): 50 -> 48, sigmoid
    for (int i = tid; i < 16*48; i += 256) {
        const int o = i / 48, t = i % 48;
        float acc = b1[o];
        #pragma unroll
        for (int cc = 0; cc < 2; ++cc)
            #pragma unroll
            for (int k = 0; k < 3; ++k)
                acc += zl[cc][t+k] * W1[o*6 + cc*3 + k];
        s1[o][t] = 1.f / (1.f + __expf(-acc));
    }
    __syncthreads();
    // maxpool3: 48 -> 16
    for (int i = tid; i < 16*16; i += 256) {
        const int o = i / 16, u = i % 16;
        p1[o][u] = fmaxf(fmaxf(s1[o][3*u], s1[o][3*u+1]), s1[o][3*u+2]);
    }
    __syncthreads();
    // conv2 (16->32, K=3, pad 0): 16 -> 14, sigmoid
    for (int i = tid; i < 32*14; i += 256) {
        const int o = i / 14, t = i % 14;
        float acc = b2[o];
        for (int cc = 0; cc < 16; ++cc)
            #pragma unroll
            for (int k = 0; k < 3; ++k)
                acc += p1[cc][t+k] * W2[o*48 + cc*3 + k];
        s2[o][t] = 1.f / (1.f + __expf(-acc));
    }
    __syncthreads();
    // maxpool3 (floor): 14 -> 4, flatten [32,4] -> 128
    for (int i = tid; i < 128; i += 256) {
        const int o = i / 4, u = i % 4;
        hflat[i] = fmaxf(fmaxf(s2[o][3*u], s2[o][3*u+1]), s2[o][3*u+2]);
    }
    __syncthreads();
    // fc1 + relu
    if (tid < 32) {
        float acc = b3[tid];
        for (int j = 0; j < 128; ++j) acc += hflat[j] * W3[tid*128 + j];
        h1[tid] = fmaxf(acc, 0.f);
    }
    __syncthreads();
    // fc2
    if (tid < 2) {
        float acc = b4[tid];
        for (int j = 0; j < 32; ++j) acc += h1[j] * W4[tid*32 + j];
        out[b*2 + tid] = acc;
    }
}

extern "C" void kernel_launch(void* const* d_in, const int* in_sizes, int n_in,
                              void* d_out, int out_size, void* d_ws, size_t ws_size,
                              hipStream_t stream) {
    const float* xi   = (const float*)d_in[0];
    const float* Sw   = (const float*)d_in[1];
    const float* tmpl = (const float*)d_in[2];
    const float* hh   = (const float*)d_in[3];
    const float* W1   = (const float*)d_in[4];
    const float* b1   = (const float*)d_in[5];
    const float* W2   = (const float*)d_in[6];
    const float* b2   = (const float*)d_in[7];
    const float* W3   = (const float*)d_in[8];
    const float* b3   = (const float*)d_in[9];
    const float* W4   = (const float*)d_in[10];
    const float* b4   = (const float*)d_in[11];
    float* out = (float*)d_out;

    float2* spec = (float2*)d_ws;
    float*  zarr = (float*)d_ws + (size_t)NSIG * SPEC_STRIDE * 2;

    fwd_fft_kernel<<<dim3(NSIG), dim3(512), 0, stream>>>(xi, Sw, tmpl, spec);
    inv_fft_kernel<<<dim3(BB * NTPL * 2), dim3(512), 0, stream>>>(spec, hh, zarr);
    head_kernel<<<dim3(BB), dim3(256), 0, stream>>>(zarr, W1, b1, W2, b2, W3, b3, W4, b4, out);
}

// Round 2
// 248.342 us; speedup vs baseline: 1.0639x; 1.0639x over previous
//
#include <hip/hip_runtime.h>
#include <math.h>

#define L_LEN 16384
#define M_LEN 8192
#define KT_LEN 4096
#define BB 32
#define NTPL 50
#define SPEC_STRIDE 8224   // complex slots per signal (>= 8193)
#define NSIG 166           // 64 x-signals + 2 w-signals + 100 templates

__device__ __forceinline__ float2 cmul(float2 a, float2 b) {
    return make_float2(a.x*b.x - a.y*b.y, a.x*b.y + a.y*b.x);
}
__device__ __forceinline__ float2 cmulc(float2 a, float2 b) { // a * conj(b)
    return make_float2(a.x*b.x + a.y*b.y, a.y*b.x - a.x*b.y);
}
// LDS bank-swizzle: bijective, keeps array at exactly 8192 float2 (64 KB).
__device__ __forceinline__ int swz(int i) { return i ^ ((i >> 4) & 15); }

// Position of frequency f after 6 radix-4 DIF stages + 1 radix-2 (digit-reverse).
__device__ __forceinline__ int pos4(int f) {
    return ((f & 3) << 11) | (((f >> 2) & 3) << 9) | (((f >> 4) & 3) << 7) |
           (((f >> 6) & 3) << 5) | (((f >> 8) & 3) << 3) |
           (((f >> 10) & 3) << 1) | ((f >> 12) & 1);
}

// T16[k] = e^{-2*pi*i*k/16384}, k in [0,16384)
__global__ __launch_bounds__(512)
void twiddle_init(float2* __restrict__ T) {
    const int k = blockIdx.x * 512 + threadIdx.x;
    const double a = -M_PI * (double)k / 8192.0;
    T[k] = make_float2((float)cos(a), (float)sin(a));
}

// In-place 8192-pt complex DIF FFT in LDS (swizzled), 6 radix-4 + 1 radix-2.
// SIGN=-1: forward (e^{-i}); SIGN=+1: inverse (e^{+i}).
// Output in digit-reversed order (pos4). The final radix-2 stage is NOT done
// here for SIGN=+1 (the inverse kernel fuses it with the max-reduction).
template<int SIGN, bool DO_FINAL>
__device__ __forceinline__ void fft_stages(float2* A, const float2* __restrict__ T, int tid) {
    #pragma unroll
    for (int s = 0; s < 6; ++s) {
        const int lq = 11 - 2 * s;
        const int q = 1 << lq;
        const int m = 1 << (12 - lq);   // 4096/q
        #pragma unroll 1
        for (int g = tid; g < 2048; g += 512) {
            const int j = g & (q - 1);
            const int base = ((g >> lq) << (lq + 2)) | j;
            float2 x0 = A[swz(base)];
            float2 x1 = A[swz(base + q)];
            float2 x2 = A[swz(base + 2*q)];
            float2 x3 = A[swz(base + 3*q)];
            float2 w1 = T[j * m];
            float2 w2 = T[2 * j * m];
            float2 w3 = T[3 * j * m];
            if (SIGN > 0) { w1.y = -w1.y; w2.y = -w2.y; w3.y = -w3.y; }
            float2 t0 = make_float2(x0.x + x2.x, x0.y + x2.y);
            float2 t2 = make_float2(x0.x - x2.x, x0.y - x2.y);
            float2 t1 = make_float2(x1.x + x3.x, x1.y + x3.y);
            float2 dd = make_float2(x1.x - x3.x, x1.y - x3.y);
            float2 t3 = (SIGN < 0) ? make_float2(dd.y, -dd.x)
                                   : make_float2(-dd.y, dd.x);
            float2 u1 = make_float2(t2.x + t3.x, t2.y + t3.y);
            float2 u2 = make_float2(t0.x - t1.x, t0.y - t1.y);
            float2 u3 = make_float2(t2.x - t3.x, t2.y - t3.y);
            A[swz(base)]       = make_float2(t0.x + t1.x, t0.y + t1.y);
            A[swz(base + q)]   = cmul(u1, w1);
            A[swz(base + 2*q)] = cmul(u2, w2);
            A[swz(base + 3*q)] = cmul(u3, w3);
        }
        __syncthreads();
    }
    if (DO_FINAL) {
        #pragma unroll 1
        for (int g = tid; g < 4096; g += 512) {
            float2 a = A[swz(2*g)], b = A[swz(2*g + 1)];
            A[swz(2*g)]     = make_float2(a.x + b.x, a.y + b.y);
            A[swz(2*g + 1)] = make_float2(a.x - b.x, a.y - b.y);
        }
        __syncthreads();
    }
}

// ---------------------------------------------------------------------------
// Kernel 1: forward real FFTs (length L) via half-length complex FFT.
// One block per signal; natural-order spectrum X[f], f=0..M written to spec.
// ---------------------------------------------------------------------------
__global__ __launch_bounds__(512, 4)
void fwd_fft_kernel(const float* __restrict__ xi, const float* __restrict__ w,
                    const float* __restrict__ tmpl, const float2* __restrict__ T,
                    float2* __restrict__ spec) {
    __shared__ float2 A[M_LEN];   // 64 KB, swizzled
    const int sig = blockIdx.x;
    const int tid = threadIdx.x;

    const float* src;
    int nre;
    if (sig < 64)      { src = xi   + sig * L_LEN;         nre = L_LEN; }
    else if (sig < 66) { src = w    + (sig - 64) * L_LEN;  nre = L_LEN; }
    else               { src = tmpl + (sig - 66) * KT_LEN; nre = KT_LEN; }
    const int nc = nre >> 1;
    const float2* s2 = (const float2*)src;
    for (int i = tid; i < nc; i += 512)         A[swz(i)] = s2[i];
    for (int i = nc + tid; i < M_LEN; i += 512) A[swz(i)] = make_float2(0.f, 0.f);
    __syncthreads();

    fft_stages<-1, true>(A, T, tid);

    // Untangle packed result to real-signal spectrum X[f], f = 0..M.
    float2* out = spec + (size_t)sig * SPEC_STRIDE;
    for (int f = tid; f <= M_LEN; f += 512) {
        const int fa = f & (M_LEN - 1);
        const int fb = (M_LEN - f) & (M_LEN - 1);
        float2 Za = A[swz(pos4(fa))];
        float2 Zb = A[swz(pos4(fb))];
        float2 E = make_float2(0.5f*(Za.x + Zb.x), 0.5f*(Za.y - Zb.y));
        float2 D = make_float2(Za.x - Zb.x, Za.y + Zb.y);
        float2 O = make_float2(0.5f*D.y, -0.5f*D.x);      // -i/2 * D
        float2 t = T[f];                                  // e^{-i pi f / M}
        float cs = t.x, sn = t.y;
        float2 TO = make_float2(cs*O.x - sn*O.y, cs*O.y + sn*O.x);
        out[f] = make_float2(E.x + TO.x, E.y + TO.y);
    }
}

// ---------------------------------------------------------------------------
// Kernel 1.5: per (b,c) premultiply: D[f] = X[f]*conj(W[f])*e^{-i pi k/M},
// k = (KT-2)*f mod L. In place on spec rows 0..63.
// ---------------------------------------------------------------------------
__global__ __launch_bounds__(512)
void premul_kernel(const float2* __restrict__ T, float2* __restrict__ spec) {
    const int bc = blockIdx.x;            // 0..63
    const int tid = threadIdx.x;
    const int c = bc & 1;
    float2* Xs = spec + (size_t)bc * SPEC_STRIDE;
    const float2* Ws = spec + (size_t)(64 + c) * SPEC_STRIDE;
    for (int f = tid; f <= M_LEN; f += 512) {
        float2 t = cmulc(Xs[f], Ws[f]);
        const int k = (4094 * f) & (L_LEN - 1);
        Xs[f] = cmul(t, T[k]);
    }
}

// ---------------------------------------------------------------------------
// Kernel 2: per (b,n,c): S[f] = D[f]*conj(H[f]); real inverse FFT via
// half-length complex inverse FFT (order irrelevant), then max / hh_sqrt.
// ---------------------------------------------------------------------------
__global__ __launch_bounds__(512, 4)
void inv_fft_kernel(const float2* __restrict__ spec, const float2* __restrict__ T,
                    const float* __restrict__ hh, float* __restrict__ zarr) {
    __shared__ float2 A[M_LEN];   // 64 KB, swizzled (reused for reduction)
    const int idx = blockIdx.x;
    const int c = idx & 1;
    const int n = (idx >> 1) % NTPL;
    const int b = idx / (2 * NTPL);
    const int tid = threadIdx.x;

    const float2* Ds = spec + (size_t)(b*2 + c)      * SPEC_STRIDE;
    const float2* Hs = spec + (size_t)(66 + n*2 + c) * SPEC_STRIDE;

    // Pass 1: S[f], f=0..M; S[M] kept by tid 0 (8192 % 512 == 0).
    float2 SMreg = make_float2(0.f, 0.f);
    for (int f = tid; f <= M_LEN; f += 512) {
        float2 S = cmulc(Ds[f], Hs[f]);
        if (f < M_LEN) A[swz(f)] = S; else SMreg = S;
    }
    __syncthreads();

    // Pass 2: pack Z'[f] = spectrum of the half-length complex IFFT input.
    for (int f = tid; f <= M_LEN/2; f += 512) {
        float2 Sa = A[swz(f)];
        float2 Sb = (f == 0) ? SMreg : A[swz(M_LEN - f)];
        float2 E = make_float2(0.5f*(Sa.x + Sb.x), 0.5f*(Sa.y - Sb.y));
        float2 D = make_float2(Sa.x - Sb.x, Sa.y + Sb.y);
        float2 t = T[f];                  // e^{-i pi f/M}; need e^{+i pi f/M}
        float cs = t.x, sn = -t.y;
        float2 O = make_float2(0.5f*(cs*D.x - sn*D.y), 0.5f*(cs*D.y + sn*D.x));
        float2 Zf = make_float2(E.x - O.y, E.y + O.x);
        A[swz(f)] = Zf;
        if (f > 0 && f < M_LEN/2)
            A[swz(M_LEN - f)] = make_float2(E.x + O.y, O.x - E.y);
    }
    __syncthreads();

    // Inverse FFT stages (final radix-2 fused with max below).
    fft_stages<+1, false>(A, T, tid);

    // Final radix-2 + max over all time samples (re and im of every entry).
    float m = -INFINITY;
    #pragma unroll 1
    for (int g = tid; g < 4096; g += 512) {
        float2 a = A[swz(2*g)], b = A[swz(2*g + 1)];
        m = fmaxf(m, fmaxf(fmaxf(a.x + b.x, a.y + b.y),
                           fmaxf(a.x - b.x, a.y - b.y)));
    }
    __syncthreads();   // all reads of A done before reusing it as scratch
    for (int off = 32; off > 0; off >>= 1)
        m = fmaxf(m, __shfl_xor(m, off));
    const int lane = tid & 63, wv = tid >> 6;
    float* redf = (float*)A;
    if (lane == 0) redf[wv] = m;
    __syncthreads();
    if (tid == 0) {
        float mm = redf[0];
        for (int i = 1; i < 8; ++i) mm = fmaxf(mm, redf[i]);
        zarr[(b*2 + c)*NTPL + n] = mm / ((float)M_LEN * hh[n*2 + c]);
    }
}

// ---------------------------------------------------------------------------
// Kernel 3: tiny CNN/MLP head. One block per batch element.
// ---------------------------------------------------------------------------
__global__ __launch_bounds__(256)
void head_kernel(const float* __restrict__ zarr,
                 const float* __restrict__ W1, const float* __restrict__ b1,
                 const float* __restrict__ W2, const float* __restrict__ b2,
                 const float* __restrict__ W3, const float* __restrict__ b3,
                 const float* __restrict__ W4, const float* __restrict__ b4,
                 float* __restrict__ out) {
    __shared__ float zl[2][NTPL];
    __shared__ float s1[16][48];
    __shared__ float p1[16][16];
    __shared__ float s2[32][14];
    __shared__ float hflat[128];
    __shared__ float h1[32];
    const int b = blockIdx.x, tid = threadIdx.x;

    for (int i = tid; i < 2*NTPL; i += 256) zl[i/NTPL][i%NTPL] = zarr[b*2*NTPL + i];
    __syncthreads();
    for (int i = tid; i < 16*48; i += 256) {
        const int o = i / 48, t = i % 48;
        float acc = b1[o];
        #pragma unroll
        for (int cc = 0; cc < 2; ++cc)
            #pragma unroll
            for (int k = 0; k < 3; ++k)
                acc += zl[cc][t+k] * W1[o*6 + cc*3 + k];
        s1[o][t] = 1.f / (1.f + __expf(-acc));
    }
    __syncthreads();
    for (int i = tid; i < 16*16; i += 256) {
        const int o = i / 16, u = i % 16;
        p1[o][u] = fmaxf(fmaxf(s1[o][3*u], s1[o][3*u+1]), s1[o][3*u+2]);
    }
    __syncthreads();
    for (int i = tid; i < 32*14; i += 256) {
        const int o = i / 14, t = i % 14;
        float acc = b2[o];
        for (int cc = 0; cc < 16; ++cc)
            #pragma unroll
            for (int k = 0; k < 3; ++k)
                acc += p1[cc][t+k] * W2[o*48 + cc*3 + k];
        s2[o][t] = 1.f / (1.f + __expf(-acc));
    }
    __syncthreads();
    for (int i = tid; i < 128; i += 256) {
        const int o = i / 4, u = i % 4;
        hflat[i] = fmaxf(fmaxf(s2[o][3*u], s2[o][3*u+1]), s2[o][3*u+2]);
    }
    __syncthreads();
    if (tid < 32) {
        float acc = b3[tid];
        for (int j = 0; j < 128; ++j) acc += hflat[j] * W3[tid*128 + j];
        h1[tid] = fmaxf(acc, 0.f);
    }
    __syncthreads();
    if (tid < 2) {
        float acc = b4[tid];
        for (int j = 0; j < 32; ++j) acc += h1[j] * W4[tid*32 + j];
        out[b*2 + tid] = acc;
    }
}

extern "C" void kernel_launch(void* const* d_in, const int* in_sizes, int n_in,
                              void* d_out, int out_size, void* d_ws, size_t ws_size,
                              hipStream_t stream) {
    const float* xi   = (const float*)d_in[0];
    const float* Sw   = (const float*)d_in[1];
    const float* tmpl = (const float*)d_in[2];
    const float* hh   = (const float*)d_in[3];
    const float* W1   = (const float*)d_in[4];
    const float* b1   = (const float*)d_in[5];
    const float* W2   = (const float*)d_in[6];
    const float* b2   = (const float*)d_in[7];
    const float* W3   = (const float*)d_in[8];
    const float* b3   = (const float*)d_in[9];
    const float* W4   = (const float*)d_in[10];
    const float* b4   = (const float*)d_in[11];
    float* out = (float*)d_out;

    float2* T16  = (float2*)d_ws;                       // 16384 float2 = 128 KB
    float2* spec = T16 + 16384;                         // NSIG * SPEC_STRIDE float2
    float*  zarr = (float*)(spec + (size_t)NSIG * SPEC_STRIDE);

    twiddle_init<<<dim3(32), dim3(512), 0, stream>>>(T16);
    fwd_fft_kernel<<<dim3(NSIG), dim3(512), 0, stream>>>(xi, Sw, tmpl, T16, spec);
    premul_kernel<<<dim3(64), dim3(512), 0, stream>>>(T16, spec);
    inv_fft_kernel<<<dim3(BB * NTPL * 2), dim3(512), 0, stream>>>(spec, T16, hh, zarr);
    head_kernel<<<dim3(BB), dim3(256), 0, stream>>>(zarr, W1, b1, W2, b2, W3, b3, W4, b4, out);
}